// Round 10
// baseline (248.244 us; speedup 1.0000x reference)
//
#include <hip/hip_runtime.h>
#include <hip/hip_bf16.h>
#include <stdint.h>

namespace {

constexpr int IDIM   = 512;
constexpr int ODIM   = 512;
constexpr int KTOT   = 32768;            // 2 * IDIM * 32
constexpr int BM = 128, BN = 128, BK = 64;
constexpr int SPLITK = 8;
constexpr int KCHUNK = KTOT / SPLITK;    // 4096
constexpr int NSTEP  = KCHUNK / BK;      // 64

typedef short    bf16x8 __attribute__((ext_vector_type(8)));
typedef float    f32x4  __attribute__((ext_vector_type(4)));
typedef float    f32x2  __attribute__((ext_vector_type(2)));
typedef uint32_t u32x4  __attribute__((ext_vector_type(4)));

__device__ __forceinline__ uint32_t f2bf1(float f) {
  union { float f; uint32_t u; } v; v.f = f;
  return (v.u + 0x7fffu + ((v.u >> 16) & 1u)) >> 16;   // RTNE
}
__device__ __forceinline__ uint32_t pk2(float lo, float hi) {
  return f2bf1(lo) | (f2bf1(hi) << 16);
}
// fast pack: round-half-up (+0x8000) then v_perm_b32 grabs the two high halves.
__device__ __forceinline__ uint32_t pk2f(float lo, float hi) {
  union { float f; uint32_t u; } a, b; a.f = lo; b.f = hi;
  return __builtin_amdgcn_perm(b.u + 0x8000u, a.u + 0x8000u, 0x07060302u);
}

// async global->LDS, 16B per lane; lds dest must be wave-uniform (HW adds lane*16)
__device__ __forceinline__ void gload_lds16(const void* gsrc, const char* ldsdst) {
  __builtin_amdgcn_global_load_lds(
      (const __attribute__((address_space(1))) uint32_t*)(uintptr_t)gsrc,
      (__attribute__((address_space(3))) uint32_t*)(uint32_t)(uintptr_t)ldsdst,
      16, 0, 0);
}

#define WAIT_VM(N)   asm volatile("s_waitcnt vmcnt(" #N ")" ::: "memory")
#define FENCE        asm volatile("" ::: "memory")

// ---------------- register-transpose convert: fc f32 [32768][512] -> wt bf16 [512][32768]
// (R6-verified, ~40 us)
__global__ __launch_bounds__(256) void transpose_convert_kernel(const float* __restrict__ fc,
                                                                uint16_t* __restrict__ wt) {
  const int t = threadIdx.x, lane = t & 63, wave = t >> 6;
  const int bid = blockIdx.x;
  const int ot = bid & 3;                  // 4 o-tiles of 128
  const int kt = bid >> 2;                 // 256 k-tiles of 128
  const int o0 = ot * 128 + lane * 2;
  const int kb = kt * 128 + wave * 32;     // wave covers 32 k
  const float* src = fc + (size_t)kb * ODIM + o0;
  uint32_t w0[16], w1[16];
#pragma unroll
  for (int p = 0; p < 16; ++p) {
    f32x2 a = *(const f32x2*)(src + (size_t)(2 * p) * ODIM);
    f32x2 b = *(const f32x2*)(src + (size_t)(2 * p + 1) * ODIM);
    w0[p] = pk2(a.x, b.x);
    w1[p] = pk2(a.y, b.y);
  }
  uint16_t* dst0 = wt + (size_t)o0 * KTOT + kb;
  uint16_t* dst1 = dst0 + KTOT;
#pragma unroll
  for (int c = 0; c < 4; ++c) {
    *(u32x4*)(dst0 + c * 8) = *(const u32x4*)&w0[c * 4];
    *(u32x4*)(dst1 + c * 8) = *(const u32x4*)&w1[c * 4];
  }
}

// ---------------- out[b][o] = bias[o]
__global__ __launch_bounds__(256) void init_bias_kernel(const float* __restrict__ bias,
                                                        float* __restrict__ out) {
  int i = blockIdx.x * 256 + threadIdx.x;
  ((f32x4*)out)[i] = ((const f32x4*)bias)[i & 127];
}

// ---------------- fused trig GEMM: A-fragments generated in registers (no A LDS),
// W 3-buf counted-vmcnt DMA pipeline, split-K atomic reduce.
__global__ __launch_bounds__(256, 2) void fkan_gemm_kernel(const float* __restrict__ x,
                                                           const uint16_t* __restrict__ wt,
                                                           float* __restrict__ out) {
  __shared__ char lds[49152];   // W 3-buf, 16 KB each

  const int t    = threadIdx.x;
  const int lane = t & 63;
  const int wave = t >> 6;
  const int lid  = lane & 15;   // row within 16-row m-tile
  const int hb   = lane >> 4;   // k-window selector (g0 = hb*8)

  // XCD-aware swizzle (512 % 8 == 0 -> bijective)
  int bid = blockIdx.x;
  int swz = (bid & 7) * 64 + (bid >> 3);
  const int bm = swz & 15;
  const int bn = (swz >> 4) & 3;
  const int bz = swz >> 6;

  const int row0  = bm * BM;
  const int col0  = bn * BN;
  const int kc0   = bz * KCHUNK;
  const int sflag = bz >> 2;              // 0: cos half, 1: sin half
  const int ibase = (bz & 3) * 128;

  // ---- W staging (verified R1/R7 mapping): source pre-swizzled, wave-uniform dest
  const uint16_t* wptr[4];
  int wdst[4];
#pragma unroll
  for (int q = 0; q < 4; ++q) {
    int nl   = q * 32 + wave * 8 + (lane >> 3);
    int slot = lane & 7;
    wptr[q] = wt + (size_t)(col0 + nl) * KTOT + kc0 + ((slot ^ (nl & 7)) << 3);
    wdst[q] = q * 4096 + wave * 1024;
  }

  // ---- B fragment read offsets (verified R1 path)
  const int wm = wave >> 1, wn = wave & 1;
  int bcol[4], bc7[4];
#pragma unroll
  for (int n = 0; n < 4; ++n) {
    int cc = wn * 64 + n * 16 + lid;
    bcol[n] = cc * 128; bc7[n] = cc & 7;
  }

  // ---- x base pointer (row = row0 + wm*64 + m*16 + lid; i = ibase + st*2 + ks)
  const float* xb0 = x + (size_t)(row0 + wm * 64 + lid) * IDIM + ibase;
  const float n0f = (float)(hb * 8 + 1);   // window start multiplier

  f32x4  acc[4][4] = {};
  bf16x8 af[2][4];

  auto stageW = [&](int buf) {            // stages steps in calling order
#pragma unroll
    for (int q = 0; q < 4; ++q) {
      gload_lds16(wptr[q], lds + buf * 16384 + wdst[q]);
      wptr[q] += BK;
    }
  };

  auto loadX = [&](float (&dst)[4][2], int st) {
#pragma unroll
    for (int m = 0; m < 4; ++m) {
      const float* p = xb0 + (size_t)(m * 16) * IDIM + st * 2;
      dst[m][0] = p[0]; dst[m][1] = p[1];   // merges to one 8B load
    }
  };

  // A-fragment generation: per (m,ks), seed window at n0 = hb*8+1 via
  // sincos(x), sincos(n0*x), angle-subtract; 7-step Chebyshev chain.
  auto genAll = [&](const float (&xc)[4][2]) {
#pragma unroll
    for (int m = 0; m < 4; ++m) {
#pragma unroll
      for (int ks = 0; ks < 2; ++ks) {
        float xx = xc[m][ks];
        float s1, c1; __sincosf(xx, &s1, &c1);
        float sn, cn; __sincosf(n0f * xx, &sn, &cn);
        const float k2 = 2.f * c1;
        float cur, prev;
        if (sflag == 0) { cur = cn; prev = fmaf(cn, c1,  sn * s1); }  // cos((n0-1)x)
        else            { cur = sn; prev = fmaf(sn, c1, -cn * s1); }  // sin((n0-1)x)
        float v[8];
        v[0] = cur;
#pragma unroll
        for (int j = 1; j < 8; ++j) {
          float nx = fmaf(k2, cur, -prev);
          prev = cur; cur = nx; v[j] = nx;
        }
        union { u32x4 u4; bf16x8 b8; } cvt;
#pragma unroll
        for (int u = 0; u < 4; ++u)
          cvt.u4[u] = pk2f(v[2 * u], v[2 * u + 1]);
        af[ks][m] = cvt.b8;
      }
    }
  };

  auto compute = [&](int wbuf) {
    const char* wb = lds + wbuf * 16384;
#pragma unroll
    for (int ks = 0; ks < 2; ++ks) {
      const int ksb = ks * 4 + hb;
      bf16x8 bfr[4];
#pragma unroll
      for (int n = 0; n < 4; ++n)
        bfr[n] = *(const bf16x8*)(wb + bcol[n] + ((ksb ^ bc7[n]) << 4));
#pragma unroll
      for (int m = 0; m < 4; ++m)
#pragma unroll
        for (int n = 0; n < 4; ++n)
          acc[m][n] = __builtin_amdgcn_mfma_f32_16x16x32_bf16(af[ks][m], bfr[n], acc[m][n], 0, 0, 0);
    }
  };

  float xA[4][2], xB[4][2];

  // ---- prologue
  loadX(xA, 0);
  stageW(0);                 // step 0
  stageW(1);                 // step 1
  WAIT_VM(4);                // step-0 W (and xA) landed; step-1's 4 may fly
  __builtin_amdgcn_s_barrier();
  FENCE;

  auto iter = [&](int st, const float (&xcur)[4][2], float (&xnxt)[4][2]) {
    if (st + 2 < NSTEP) stageW((st + 2) % 3);     // 4 DMA
    if (st + 1 < NSTEP) loadX(xnxt, st + 1);      // 4 loads
    genAll(xcur);
    compute(st % 3);
    if (st + 1 < NSTEP) {
      WAIT_VM(8);            // allow this iter's 4 DMA + 4 x-loads; older all done
      __builtin_amdgcn_s_barrier();
      FENCE;
    }
  };

#pragma unroll 1
  for (int st2 = 0; st2 < NSTEP; st2 += 2) {      // 2x unroll: static x-buf names
    iter(st2,     xA, xB);
    iter(st2 + 1, xB, xA);
  }

  // ---- epilogue: split-K reduce via atomics (out pre-initialized with bias)
#pragma unroll
  for (int m = 0; m < 4; ++m) {
#pragma unroll
    for (int n = 0; n < 4; ++n) {
      int rr = row0 + wm * 64 + m * 16 + ((lane >> 4) << 2);
      int cc = col0 + wn * 64 + n * 16 + lid;
#pragma unroll
      for (int j = 0; j < 4; ++j)
        atomicAdd(out + (size_t)(rr + j) * ODIM + cc, acc[m][n][j]);
    }
  }
}

}  // namespace

extern "C" void kernel_launch(void* const* d_in, const int* in_sizes, int n_in,
                              void* d_out, int out_size, void* d_ws, size_t ws_size,
                              hipStream_t stream) {
  const float* x    = (const float*)d_in[0];
  const float* fc   = (const float*)d_in[1];   // [2,512,32,512] == [32768][512]
  const float* bias = (const float*)d_in[2];
  float*    out = (float*)d_out;
  uint16_t* wt  = (uint16_t*)d_ws;             // 33.5 MB bf16, o-major

  transpose_convert_kernel<<<1024, 256, 0, stream>>>(fc, wt);
  init_bias_kernel<<<1024, 256, 0, stream>>>(bias, out);
  fkan_gemm_kernel<<<512, 256, 0, stream>>>(x, wt, out);
}